// Round 1
// baseline (211.539 us; speedup 1.0000x reference)
//
#include <hip/hip_runtime.h>
#include <hip/hip_bf16.h>

// Problem constants (reference: N=16384, D=128, T=0.07)
#define NROWS 16384
#define DDIM  128
constexpr float TEMP = 0.07f;

constexpr int BM = 128;            // rows per block
constexpr int BN = 64;             // cols per j-tile
constexpr int JSPLIT = 4;          // column splits (grid = 128*4 = 512 blocks)
constexpr int JCOLS = NROWS / JSPLIT;   // 4096 cols per block
constexpr int LDB = DDIM + 8;      // padded LDS row stride in ushorts (272 B -> 2-way bank alias = free)

typedef __attribute__((ext_vector_type(8))) short bf16x8;  // 8 bf16 = 4 VGPRs (MFMA A/B frag)
typedef __attribute__((ext_vector_type(4))) float f32x4;   // MFMA C/D frag

// round-to-nearest-even fp32 -> bf16 (bit manipulation; no API dependency)
__device__ __forceinline__ unsigned short f2b(float f) {
  unsigned int u = __float_as_uint(f);
  u += 0x7fffu + ((u >> 16) & 1u);
  return (unsigned short)(u >> 16);
}

__global__ void convert_k(const float* __restrict__ x, unsigned short* __restrict__ xb) {
  int i = (blockIdx.x * blockDim.x + threadIdx.x) * 4;
  float4 v = *(const float4*)(x + i);
  ushort4 o;
  o.x = f2b(v.x); o.y = f2b(v.y); o.z = f2b(v.z); o.w = f2b(v.w);
  *(ushort4*)(xb + i) = o;
}

// Fused Gram x x^T / T -> exp -> row-sum.
// Block: 256 threads = 4 waves. Wave w: rows [wr, wr+64), cols (w&1)*32 within the 64-col tile.
// A-panel (128 rows x K=128) register-resident per wave (its 64 rows).
// B-tile (64 rows x K=128 of x) staged in LDS per j-step.
__global__ void gram_lse_k(const unsigned short* __restrict__ xb, float* __restrict__ rowsum) {
  __shared__ unsigned short lB[BN * LDB];
  const int tid = threadIdx.x;
  const int wave = tid >> 6, lane = tid & 63;
  const int l15 = lane & 15, q = lane >> 4;
  const int rb = (int)(blockIdx.x / JSPLIT) * BM;
  const int cb = (int)(blockIdx.x % JSPLIT) * JCOLS;
  const int wr = rb + (wave >> 1) * 64;   // this wave's row base
  const int wc = (wave & 1) * 32;         // this wave's col offset in tile
  const float invT = 1.0f / TEMP;

  // A fragments: 4 row-tiles x 4 k-tiles, 16B contiguous per lane.
  // 16x16x32 A layout: A[m = lane&15][k = (lane>>4)*8 + j], j=0..7
  bf16x8 af[4][4];
#pragma unroll
  for (int rt = 0; rt < 4; ++rt)
#pragma unroll
    for (int kt = 0; kt < 4; ++kt)
      af[rt][kt] = *(const bf16x8*)(xb + (wr + rt * 16 + l15) * DDIM + kt * 32 + q * 8);

  // per-lane running row sums: rows wr + rt*16 + q*4 + r
  float rs[4][4];
#pragma unroll
  for (int rt = 0; rt < 4; ++rt)
#pragma unroll
    for (int r = 0; r < 4; ++r) rs[rt][r] = 0.f;

  for (int t = 0; t < JCOLS / BN; ++t) {
    const int col0 = cb + t * BN;
    __syncthreads();  // previous tile's readers done
    // stage 64x128 bf16 B-tile (16 KB) -> LDS, 4 x int4 per thread, coalesced
#pragma unroll
    for (int c = tid; c < BN * 16; c += 256) {
      int row = c >> 4, ch = c & 15;
      *(int4*)(lB + row * LDB + ch * 8) = *(const int4*)(xb + (col0 + row) * DDIM + ch * 8);
    }
    __syncthreads();

    // B fragments: B[k][n] with n = lane&15 (= col), k = (lane>>4)*8+j -> same 16B-contig pattern
    bf16x8 bf[2][4];
#pragma unroll
    for (int ct = 0; ct < 2; ++ct)
#pragma unroll
      for (int kt = 0; kt < 4; ++kt)
        bf[ct][kt] = *(const bf16x8*)(lB + (wc + ct * 16 + l15) * LDB + kt * 32 + q * 8);

    f32x4 acc[4][2];
#pragma unroll
    for (int rt = 0; rt < 4; ++rt)
#pragma unroll
      for (int ct = 0; ct < 2; ++ct) {
        f32x4 a = {0.f, 0.f, 0.f, 0.f};
#pragma unroll
        for (int kt = 0; kt < 4; ++kt)
          a = __builtin_amdgcn_mfma_f32_16x16x32_bf16(af[rt][kt], bf[ct][kt], a, 0, 0, 0);
        acc[rt][ct] = a;
      }

    // epilogue: exp((sim - 1)/T), accumulate into per-row sums
    // C/D layout (m89-verified): col = lane&15, row = (lane>>4)*4 + reg
#pragma unroll
    for (int rt = 0; rt < 4; ++rt)
#pragma unroll
      for (int ct = 0; ct < 2; ++ct)
#pragma unroll
        for (int r = 0; r < 4; ++r)
          rs[rt][r] += __expf((acc[rt][ct][r] - 1.0f) * invT);
  }

  // reduce across the 16 lanes (cols) sharing each row: xor masks 1,2,4,8 stay within quad-group
#pragma unroll
  for (int m = 1; m <= 8; m <<= 1)
#pragma unroll
    for (int rt = 0; rt < 4; ++rt)
#pragma unroll
      for (int r = 0; r < 4; ++r)
        rs[rt][r] += __shfl_xor(rs[rt][r], m, 64);

  if (l15 == 0) {
#pragma unroll
    for (int rt = 0; rt < 4; ++rt)
#pragma unroll
      for (int r = 0; r < 4; ++r)
        atomicAdd(&rowsum[wr + rt * 16 + q * 4 + r], rs[rt][r]);
  }
}

__global__ void finalize_k(const float* __restrict__ rowsum, float* __restrict__ out) {
  __shared__ float red[4];
  const int tid = threadIdx.x;
  float s = 0.f;
  for (int i = tid; i < NROWS; i += 256) s += __logf(rowsum[i]);
#pragma unroll
  for (int m = 1; m < 64; m <<= 1) s += __shfl_xor(s, m, 64);
  if ((tid & 63) == 0) red[tid >> 6] = s;
  __syncthreads();
  if (tid == 0) out[0] = 1.0f / TEMP + (red[0] + red[1] + red[2] + red[3]) / (float)NROWS;
}

extern "C" void kernel_launch(void* const* d_in, const int* in_sizes, int n_in,
                              void* d_out, int out_size, void* d_ws, size_t ws_size,
                              hipStream_t stream) {
  const float* x = (const float*)d_in[0];
  float* out = (float*)d_out;
  unsigned short* xb = (unsigned short*)d_ws;                       // 16384*128*2 = 4 MB
  float* rowsum = (float*)((char*)d_ws + (size_t)NROWS * DDIM * 2); // 64 KB

  hipMemsetAsync(rowsum, 0, NROWS * sizeof(float), stream);
  convert_k<<<NROWS * DDIM / (256 * 4), 256, 0, stream>>>(x, xb);
  gram_lse_k<<<(NROWS / BM) * JSPLIT, 256, 0, stream>>>(xb, rowsum);
  finalize_k<<<1, 256, 0, stream>>>(rowsum, out);
}

// Round 2
// 206.639 us; speedup vs baseline: 1.0237x; 1.0237x over previous
//
#include <hip/hip_runtime.h>
#include <hip/hip_bf16.h>
#include <math.h>

// Problem constants (reference: N=16384, D=128, T=0.07)
#define NROWS 16384
#define DDIM  128
constexpr float TEMP = 0.07f;

constexpr int BM = 128;                 // rows per block
constexpr int BN = 64;                  // cols per j-tile
constexpr int JSPLIT = 16;              // column splits (grid = 128*16 = 2048 blocks -> 8 blocks/CU)
constexpr int JCOLS = NROWS / JSPLIT;   // 1024 cols per block

typedef __attribute__((ext_vector_type(8))) short bf16x8;  // 8 bf16 = 4 VGPRs (MFMA A/B frag)
typedef __attribute__((ext_vector_type(4))) float f32x4;   // MFMA C/D frag

// round-to-nearest-even fp32 -> bf16
__device__ __forceinline__ unsigned short f2b(float f) {
  unsigned int u = __float_as_uint(f);
  u += 0x7fffu + ((u >> 16) & 1u);
  return (unsigned short)(u >> 16);
}

__global__ void convert_k(const float* __restrict__ x, unsigned short* __restrict__ xb) {
  int i = (blockIdx.x * blockDim.x + threadIdx.x) * 4;
  float4 v = *(const float4*)(x + i);
  ushort4 o;
  o.x = f2b(v.x); o.y = f2b(v.y); o.z = f2b(v.z); o.w = f2b(v.w);
  *(ushort4*)(xb + i) = o;
}

// Fused Gram x x^T / T -> exp -> row-sum.  NO LDS, NO barriers:
// B-fragments load straight from global (xb is 4 MB -> L2-resident; each
// b128 load instr touches 16 rows x 64 B contiguous). 2048 blocks of 4 waves;
// wave w: rows [wr, wr+64), cols (w&1)*32 within the 64-col tile.
__global__ __launch_bounds__(256, 3)
void gram_lse_k(const unsigned short* __restrict__ xb, float* __restrict__ rowsum) {
  const int tid = threadIdx.x;
  const int wave = tid >> 6, lane = tid & 63;
  const int l15 = lane & 15, q = lane >> 4;
  const int rb = (int)(blockIdx.x / JSPLIT) * BM;
  const int cb = (int)(blockIdx.x % JSPLIT) * JCOLS;
  const int wr = rb + (wave >> 1) * 64;   // this wave's row base
  const int wc = (wave & 1) * 32;         // this wave's col offset in tile

  // exp((sim-1)/T) = exp2(sim*S - S), S = log2(e)/T
  const float S = 1.44269504088896f / TEMP;

  // A fragments: 4 row-tiles x 4 k-tiles, register-resident for the whole kernel.
  // 16x16x32 A layout: A[m = lane&15][k = (lane>>4)*8 + j], j=0..7 (16B contiguous)
  bf16x8 af[4][4];
#pragma unroll
  for (int rt = 0; rt < 4; ++rt)
#pragma unroll
    for (int kt = 0; kt < 4; ++kt)
      af[rt][kt] = *(const bf16x8*)(xb + (wr + rt * 16 + l15) * DDIM + kt * 32 + q * 8);

  // per-lane running row sums: rows wr + rt*16 + q*4 + r
  float rs[4][4];
#pragma unroll
  for (int rt = 0; rt < 4; ++rt)
#pragma unroll
    for (int r = 0; r < 4; ++r) rs[rt][r] = 0.f;

  for (int t = 0; t < JCOLS / BN; ++t) {
    // B fragments straight from global: B[k][n=col], col = base + ct*16 + l15,
    // k = kt*32 + q*8 + j  -> 16B contiguous per lane (same pattern as A).
    const unsigned short* bp = xb + (size_t)(cb + t * BN + wc + l15) * DDIM + q * 8;
    bf16x8 bf[2][4];
#pragma unroll
    for (int ct = 0; ct < 2; ++ct)
#pragma unroll
      for (int kt = 0; kt < 4; ++kt)
        bf[ct][kt] = *(const bf16x8*)(bp + ct * 16 * DDIM + kt * 32);

    f32x4 acc[4][2];
#pragma unroll
    for (int rt = 0; rt < 4; ++rt)
#pragma unroll
      for (int ct = 0; ct < 2; ++ct) {
        f32x4 a = {0.f, 0.f, 0.f, 0.f};
#pragma unroll
        for (int kt = 0; kt < 4; ++kt)
          a = __builtin_amdgcn_mfma_f32_16x16x32_bf16(af[rt][kt], bf[ct][kt], a, 0, 0, 0);
        acc[rt][ct] = a;
      }

    // epilogue: rs += exp2(sim*S - S).  C/D layout: col=lane&15, row=(lane>>4)*4+reg
#pragma unroll
    for (int rt = 0; rt < 4; ++rt)
#pragma unroll
      for (int ct = 0; ct < 2; ++ct)
#pragma unroll
        for (int r = 0; r < 4; ++r)
          rs[rt][r] += exp2f(fmaf(acc[rt][ct][r], S, -S));
  }

  // reduce across the 16 lanes (cols) sharing each row
#pragma unroll
  for (int m = 1; m <= 8; m <<= 1)
#pragma unroll
    for (int rt = 0; rt < 4; ++rt)
#pragma unroll
      for (int r = 0; r < 4; ++r)
        rs[rt][r] += __shfl_xor(rs[rt][r], m, 64);

  if (l15 == 0) {
#pragma unroll
    for (int rt = 0; rt < 4; ++rt)
#pragma unroll
      for (int r = 0; r < 4; ++r)
        atomicAdd(&rowsum[wr + rt * 16 + q * 4 + r], rs[rt][r]);
  }
}

// Stage 1: 64 blocks, each reduces 256 rows' log(rowsum) and atomically adds to accum.
__global__ void finalize1_k(const float* __restrict__ rowsum, float* __restrict__ accum) {
  __shared__ float red[4];
  const int tid = threadIdx.x;
  float s = __logf(rowsum[blockIdx.x * 256 + tid]);
#pragma unroll
  for (int m = 1; m < 64; m <<= 1) s += __shfl_xor(s, m, 64);
  if ((tid & 63) == 0) red[tid >> 6] = s;
  __syncthreads();
  if (tid == 0) atomicAdd(accum, red[0] + red[1] + red[2] + red[3]);
}

// Stage 2: single thread writes the scalar.
__global__ void finalize2_k(const float* __restrict__ accum, float* __restrict__ out) {
  out[0] = 1.0f / TEMP + accum[0] / (float)NROWS;
}

extern "C" void kernel_launch(void* const* d_in, const int* in_sizes, int n_in,
                              void* d_out, int out_size, void* d_ws, size_t ws_size,
                              hipStream_t stream) {
  const float* x = (const float*)d_in[0];
  float* out = (float*)d_out;
  unsigned short* xb = (unsigned short*)d_ws;                       // 16384*128*2 = 4 MB
  float* rowsum = (float*)((char*)d_ws + (size_t)NROWS * DDIM * 2); // 64 KB
  float* accum = rowsum + NROWS;                                    // 1 float

  hipMemsetAsync(rowsum, 0, (NROWS + 1) * sizeof(float), stream);
  convert_k<<<NROWS * DDIM / (256 * 4), 256, 0, stream>>>(x, xb);
  gram_lse_k<<<(NROWS / BM) * JSPLIT, 256, 0, stream>>>(xb, rowsum);
  finalize1_k<<<NROWS / 256, 256, 0, stream>>>(rowsum, accum);
  finalize2_k<<<1, 1, 0, stream>>>(accum, out);
}

// Round 3
// 193.712 us; speedup vs baseline: 1.0920x; 1.0667x over previous
//
#include <hip/hip_runtime.h>
#include <hip/hip_bf16.h>
#include <math.h>

// Problem constants (reference: N=16384, D=128, T=0.07)
#define NROWS 16384
#define DDIM  128
constexpr float TEMP = 0.07f;
// Pre-scale trick: scale x by sqrt(S), S = log2(e)/T. Then MFMA yields
// acc = S * <x_i,x_j> and row_lse = ln(sum_j exp2(acc)) EXACTLY (max term
// 2^20.6 ~ 1.6e6, no overflow) -> epilogue is just exp2 + add.
constexpr float S_EXP = 1.44269504088896f / TEMP;   // 20.60993

constexpr int BM = 128;                 // rows per block
constexpr int BN = 64;                  // cols per j-tile
constexpr int JSPLIT = 16;              // grid = 128*16 = 2048 blocks
constexpr int JCOLS = NROWS / JSPLIT;   // 1024 cols per block

typedef __attribute__((ext_vector_type(8))) short bf16x8;  // MFMA A/B frag
typedef __attribute__((ext_vector_type(4))) float f32x4;   // MFMA C/D frag

// round-to-nearest-even fp32 -> bf16
__device__ __forceinline__ unsigned short f2b(float f) {
  unsigned int u = __float_as_uint(f);
  u += 0x7fffu + ((u >> 16) & 1u);
  return (unsigned short)(u >> 16);
}

// Convert + pre-scale; also zero rowsum/accum/cnt (replaces a memset dispatch).
__global__ void convert_k(const float* __restrict__ x, unsigned short* __restrict__ xb,
                          float* __restrict__ rowsum, float* __restrict__ accum,
                          int* __restrict__ cnt) {
  const float R = 4.53981419f;  // sqrt(S_EXP)
  int i = (blockIdx.x * blockDim.x + threadIdx.x) * 4;
  float4 v = *(const float4*)(x + i);
  ushort4 o;
  o.x = f2b(v.x * R); o.y = f2b(v.y * R); o.z = f2b(v.z * R); o.w = f2b(v.w * R);
  *(ushort4*)(xb + i) = o;
  if (blockIdx.x < 16) {
    float4 z = {0.f, 0.f, 0.f, 0.f};
    *(float4*)(rowsum + blockIdx.x * 1024 + threadIdx.x * 4) = z;
  }
  if (blockIdx.x == 16 && threadIdx.x == 0) { *accum = 0.f; *cnt = 0; }
}

// Fused Gram -> exp2 -> row-sum. No LDS. B-frags straight from L2-resident xb.
// Block: 4 waves; wave w: rows [wr,wr+64), cols (w&1)*32 of the 64-col tile.
// ct/rt streamed so live regs ~= af(64)+bf(16)+acc(4)+rs(16)+addr -> 4 waves/SIMD.
__global__ __launch_bounds__(256, 4)
void gram_lse_k(const unsigned short* __restrict__ xb, float* __restrict__ rowsum) {
  const int tid = threadIdx.x;
  const int wave = tid >> 6, lane = tid & 63;
  const int l15 = lane & 15, q = lane >> 4;
  const int rb = (int)(blockIdx.x / JSPLIT) * BM;
  const int cb = (int)(blockIdx.x % JSPLIT) * JCOLS;
  const int wr = rb + (wave >> 1) * 64;
  const int wc = (wave & 1) * 32;

  // A frags: 16x16x32 layout A[m=lane&15][k=(lane>>4)*8+j] -> 16B contiguous
  bf16x8 af[4][4];
#pragma unroll
  for (int rt = 0; rt < 4; ++rt)
#pragma unroll
    for (int kt = 0; kt < 4; ++kt)
      af[rt][kt] = *(const bf16x8*)(xb + (wr + rt * 16 + l15) * DDIM + kt * 32 + q * 8);

  float rs[4][4];
#pragma unroll
  for (int rt = 0; rt < 4; ++rt)
#pragma unroll
    for (int r = 0; r < 4; ++r) rs[rt][r] = 0.f;

  for (int t = 0; t < JCOLS / BN; ++t) {
    const unsigned short* bp0 = xb + (size_t)(cb + t * BN + wc + l15) * DDIM + q * 8;
#pragma unroll
    for (int ct = 0; ct < 2; ++ct) {
      const unsigned short* bp = bp0 + ct * 16 * DDIM;
      bf16x8 bf[4];
#pragma unroll
      for (int kt = 0; kt < 4; ++kt)
        bf[kt] = *(const bf16x8*)(bp + kt * 32);
#pragma unroll
      for (int rt = 0; rt < 4; ++rt) {
        f32x4 a = {0.f, 0.f, 0.f, 0.f};
#pragma unroll
        for (int kt = 0; kt < 4; ++kt)
          a = __builtin_amdgcn_mfma_f32_16x16x32_bf16(af[rt][kt], bf[kt], a, 0, 0, 0);
        // C/D layout: col=lane&15, row=(lane>>4)*4+reg. rs += exp2(acc), no fma.
#pragma unroll
        for (int r = 0; r < 4; ++r)
          rs[rt][r] += __builtin_amdgcn_exp2f(a[r]);
      }
    }
  }

  // reduce across the 16 lanes (cols) sharing each row
#pragma unroll
  for (int m = 1; m <= 8; m <<= 1)
#pragma unroll
    for (int rt = 0; rt < 4; ++rt)
#pragma unroll
      for (int r = 0; r < 4; ++r)
        rs[rt][r] += __shfl_xor(rs[rt][r], m, 64);

  if (l15 == 0) {
#pragma unroll
    for (int rt = 0; rt < 4; ++rt)
#pragma unroll
      for (int r = 0; r < 4; ++r)
        atomicAdd(&rowsum[wr + rt * 16 + q * 4 + r], rs[rt][r]);
  }
}

// Single finalize: 64 blocks reduce ln(rowsum); last block writes the scalar.
// loss = mean_i ln(rowsum_i)  (the 1/T shift cancelled into the pre-scale).
__global__ void finalize_k(const float* __restrict__ rowsum, float* __restrict__ accum,
                           int* __restrict__ cnt, float* __restrict__ out) {
  __shared__ float red[4];
  const int tid = threadIdx.x;
  float s = __logf(rowsum[blockIdx.x * 256 + tid]);
#pragma unroll
  for (int m = 1; m < 64; m <<= 1) s += __shfl_xor(s, m, 64);
  if ((tid & 63) == 0) red[tid >> 6] = s;
  __syncthreads();
  if (tid == 0) {
    atomicAdd(accum, red[0] + red[1] + red[2] + red[3]);
    __threadfence();
    int prev = atomicAdd(cnt, 1);
    if (prev == (int)gridDim.x - 1) {
      __threadfence();
      float a = __hip_atomic_load(accum, __ATOMIC_RELAXED, __HIP_MEMORY_SCOPE_AGENT);
      out[0] = a / (float)NROWS;
    }
  }
}

extern "C" void kernel_launch(void* const* d_in, const int* in_sizes, int n_in,
                              void* d_out, int out_size, void* d_ws, size_t ws_size,
                              hipStream_t stream) {
  const float* x = (const float*)d_in[0];
  float* out = (float*)d_out;
  unsigned short* xb = (unsigned short*)d_ws;                       // 4 MB
  float* rowsum = (float*)((char*)d_ws + (size_t)NROWS * DDIM * 2); // 64 KB
  float* accum = rowsum + NROWS;
  int* cnt = (int*)(accum + 1);

  convert_k<<<NROWS * DDIM / (256 * 4), 256, 0, stream>>>(x, xb, rowsum, accum, cnt);
  gram_lse_k<<<(NROWS / BM) * JSPLIT, 256, 0, stream>>>(xb, rowsum);
  finalize_k<<<NROWS / 256, 256, 0, stream>>>(rowsum, accum, cnt, out);
}

// Round 4
// 140.244 us; speedup vs baseline: 1.5084x; 1.3813x over previous
//
#include <hip/hip_runtime.h>
#include <hip/hip_bf16.h>
#include <math.h>

// Problem constants (reference: N=16384, D=128, T=0.07)
#define NROWS 16384
#define DDIM  128
constexpr float TEMP = 0.07f;
// Pre-scale trick: x *= sqrt(log2(e)/T) so MFMA emits acc = S*<xi,xj> and
// row_lse = ln(sum exp2(acc)) exactly (max term 2^20.6, no overflow).
constexpr float S_EXP = 1.44269504088896f / TEMP;

constexpr int BM = 128;                 // rows per block
constexpr int BN = 64;                  // cols per j-tile
constexpr int JSPLIT = 16;              // grid = 2048 blocks
constexpr int JCOLS = NROWS / JSPLIT;   // 1024 cols per block
constexpr int NT = JCOLS / BN;          // 16 tiles

typedef __attribute__((ext_vector_type(8))) short bf16x8;
typedef __attribute__((ext_vector_type(4))) float f32x4;

__device__ __forceinline__ unsigned short f2b(float f) {
  unsigned int u = __float_as_uint(f);
  u += 0x7fffu + ((u >> 16) & 1u);
  return (unsigned short)(u >> 16);
}

// async 16B global -> LDS (lds dest = wave-uniform base + lane*16)
__device__ __forceinline__ void gload_lds16(const unsigned short* g, unsigned short* l) {
  __builtin_amdgcn_global_load_lds(
      (const __attribute__((address_space(1))) unsigned int*)g,
      (__attribute__((address_space(3))) unsigned int*)l, 16, 0, 0);
}

// Convert + pre-scale; also zero rowsum/accum/cnt.
__global__ void convert_k(const float* __restrict__ x, unsigned short* __restrict__ xb,
                          float* __restrict__ rowsum, float* __restrict__ accum,
                          int* __restrict__ cnt) {
  const float R = 4.53981419f;  // sqrt(S_EXP)
  int i = (blockIdx.x * blockDim.x + threadIdx.x) * 4;
  float4 v = *(const float4*)(x + i);
  ushort4 o;
  o.x = f2b(v.x * R); o.y = f2b(v.y * R); o.z = f2b(v.z * R); o.w = f2b(v.w * R);
  *(ushort4*)(xb + i) = o;
  if (blockIdx.x < 16) {
    float4 z = {0.f, 0.f, 0.f, 0.f};
    *(float4*)(rowsum + blockIdx.x * 1024 + threadIdx.x * 4) = z;
  }
  if (blockIdx.x == 16 && threadIdx.x == 0) { *accum = 0.f; *cnt = 0; }
}

// LDS B-tile layout: 16B chunk for logical (col, kc) [kc = k/8, 0..15] lives at
// physical chunk  p = col*16 + (kc ^ (col & 15)).
//  - staging: physical chunk c = (wave*4+it)*64 + lane  ->  col = c>>4,
//    kcLog = (c&15) ^ (col&15); per-call gaddrs cover 4 full 256B rows
//    (permuted within-row) -> fully coalesced.
//  - consumer ds_read_b128 at p*16: bank = ((kt*4+q)^l15 & 7)*4 -> 2-way only (free).
__global__ __launch_bounds__(256, 4)
void gram_lse_k(const unsigned short* __restrict__ xb, float* __restrict__ rowsum) {
  __shared__ unsigned short lB[2][BN * DDIM];   // 2 x 16 KB
  const int tid = threadIdx.x;
  const int wave = tid >> 6, lane = tid & 63;
  const int l15 = lane & 15, q = lane >> 4;
  const int rb = (int)(blockIdx.x / JSPLIT) * BM;
  const int cb = (int)(blockIdx.x % JSPLIT) * JCOLS;
  const int wr = rb + (wave >> 1) * 64;
  const int wc = (wave & 1) * 32;

  // A frags (register-resident whole kernel; 16x16x32 A: m=l15, k=q*8+j)
  bf16x8 af[4][4];
#pragma unroll
  for (int rt = 0; rt < 4; ++rt)
#pragma unroll
    for (int kt = 0; kt < 4; ++kt)
      af[rt][kt] = *(const bf16x8*)(xb + (wr + rt * 16 + l15) * DDIM + kt * 32 + q * 8);

  // staging lane constants: call it stages chunk c=(wave*4+it)*64+lane
  // col_s = wave*16 + it*4 + q ; kcLog = l15 ^ (it*4 + q)
  // prefetch tile 0 into buf 0
  {
    const unsigned short* g0 = xb + (size_t)cb * DDIM;
#pragma unroll
    for (int it = 0; it < 4; ++it) {
      int colS = wave * 16 + it * 4 + q;
      int kcLog = l15 ^ (it * 4 + q);
      gload_lds16(g0 + colS * DDIM + kcLog * 8, &lB[0][(wave * 4 + it) * 512]);
    }
  }

  float rs[4][4];
#pragma unroll
  for (int rt = 0; rt < 4; ++rt)
#pragma unroll
    for (int r = 0; r < 4; ++r) rs[rt][r] = 0.f;

  for (int t = 0; t < NT; ++t) {
    __syncthreads();                       // vmcnt drain -> buf[t&1] ready
    const unsigned short* Lc = lB[t & 1];
    unsigned short* Ln = lB[(t + 1) & 1];
    const unsigned short* gn = xb + (size_t)(cb + (t + 1) * BN) * DDIM;
    const bool pf = (t + 1 < NT);

#pragma unroll
    for (int ct = 0; ct < 2; ++ct) {
      // consumer frags from LDS (2-way bank alias only)
      bf16x8 bf[4];
#pragma unroll
      for (int kt = 0; kt < 4; ++kt)
        bf[kt] = *(const bf16x8*)&Lc[(wc + ct * 16 + l15) * DDIM +
                                     ((q ^ l15 ^ (kt << 2)) << 3)];
      // issue async stage of next tile (2 calls per ct-group)
      if (pf) {
#pragma unroll
        for (int i2 = 0; i2 < 2; ++i2) {
          int it = ct * 2 + i2;
          int colS = wave * 16 + it * 4 + q;
          int kcLog = l15 ^ (it * 4 + q);
          gload_lds16(gn + colS * DDIM + kcLog * 8, &Ln[(wave * 4 + it) * 512]);
        }
      }
      // MFMA + exp2 epilogue (C/D: col=l15, row=q*4+reg)
#pragma unroll
      for (int rt = 0; rt < 4; ++rt) {
        f32x4 a = {0.f, 0.f, 0.f, 0.f};
#pragma unroll
        for (int kt = 0; kt < 4; ++kt)
          a = __builtin_amdgcn_mfma_f32_16x16x32_bf16(af[rt][kt], bf[kt], a, 0, 0, 0);
#pragma unroll
        for (int r = 0; r < 4; ++r)
          rs[rt][r] += __builtin_amdgcn_exp2f(a[r]);
      }
    }
  }

  // reduce across the 16 lanes (cols) sharing each row
#pragma unroll
  for (int m = 1; m <= 8; m <<= 1)
#pragma unroll
    for (int rt = 0; rt < 4; ++rt)
#pragma unroll
      for (int r = 0; r < 4; ++r)
        rs[rt][r] += __shfl_xor(rs[rt][r], m, 64);

  if (l15 == 0) {
#pragma unroll
    for (int rt = 0; rt < 4; ++rt)
#pragma unroll
      for (int r = 0; r < 4; ++r)
        atomicAdd(&rowsum[wr + rt * 16 + q * 4 + r], rs[rt][r]);
  }
}

// 64 blocks reduce ln(rowsum); last block writes the scalar.
__global__ void finalize_k(const float* __restrict__ rowsum, float* __restrict__ accum,
                           int* __restrict__ cnt, float* __restrict__ out) {
  __shared__ float red[4];
  const int tid = threadIdx.x;
  float s = __logf(rowsum[blockIdx.x * 256 + tid]);
#pragma unroll
  for (int m = 1; m < 64; m <<= 1) s += __shfl_xor(s, m, 64);
  if ((tid & 63) == 0) red[tid >> 6] = s;
  __syncthreads();
  if (tid == 0) {
    atomicAdd(accum, red[0] + red[1] + red[2] + red[3]);
    __threadfence();
    int prev = atomicAdd(cnt, 1);
    if (prev == (int)gridDim.x - 1) {
      __threadfence();
      float a = __hip_atomic_load(accum, __ATOMIC_RELAXED, __HIP_MEMORY_SCOPE_AGENT);
      out[0] = a / (float)NROWS;
    }
  }
}

extern "C" void kernel_launch(void* const* d_in, const int* in_sizes, int n_in,
                              void* d_out, int out_size, void* d_ws, size_t ws_size,
                              hipStream_t stream) {
  const float* x = (const float*)d_in[0];
  float* out = (float*)d_out;
  unsigned short* xb = (unsigned short*)d_ws;                       // 4 MB
  float* rowsum = (float*)((char*)d_ws + (size_t)NROWS * DDIM * 2); // 64 KB
  float* accum = rowsum + NROWS;
  int* cnt = (int*)(accum + 1);

  convert_k<<<NROWS * DDIM / (256 * 4), 256, 0, stream>>>(x, xb, rowsum, accum, cnt);
  gram_lse_k<<<(NROWS / BM) * JSPLIT, 256, 0, stream>>>(xb, rowsum);
  finalize_k<<<NROWS / 256, 256, 0, stream>>>(rowsum, accum, cnt, out);
}